// Round 1
// baseline (801.426 us; speedup 1.0000x reference)
//
#include <hip/hip_runtime.h>
#include <hip/hip_bf16.h>

// SNN EventProp LIF forward, 2 layers: 784 -> 1024 -> 256, T=100, B=256.
// Structure: the LIF current I is LINEAR in the per-step matmul results, so
// all T matmuls of a layer collapse into one big GEMM; the threshold/reset
// nonlinearity is a cheap per-(b,n) scan over t afterwards.
//
//   GEMM1: C1[25088,1024] = x[t=0..97] @ W1^T      (rows r = t*256+b)
//   scan1: S1[25344,1024]  (row block t=0 zeroed; t=1..98 computed)
//   GEMM2: C2[25344,256]  = S1 @ W2^T
//   scan2: out[100,256,256] (t=0 zero row + t=1..99)
//
// ALPHA=0.8f, BETA=0.95f, 1-BETA=0.05f (verified equal to float32 of the
// Python float64 constants).

#define ALPHA_F 0.8f
#define BETA_F 0.95f
#define ONE_MINUS_BETA_F 0.05f

// C = A @ B^T.  A: [M,K] row-major, B: [N,K] row-major, C: [M,N] row-major.
// BM=BN=128, BK=8, 256 threads, 8x8 per-thread tile. M%128==0, N%128==0, K%8==0.
__global__ __launch_bounds__(256) void sgemm_nt(const float* __restrict__ A,
                                                const float* __restrict__ B,
                                                float* __restrict__ C,
                                                int M, int N, int K) {
    __shared__ float As[8][128];
    __shared__ float Bs[8][128];
    const int bm = blockIdx.x;
    const int bn = blockIdx.y;
    const int tid = threadIdx.x;

    // loader mapping: 256 threads load 128 rows x 8 k (one float4 each)
    const int lm = tid >> 1;          // 0..127
    const int lk = (tid & 1) * 4;     // 0 or 4
    const float* Arow = A + (size_t)(bm * 128 + lm) * K + lk;
    const float* Brow = B + (size_t)(bn * 128 + lm) * K + lk;

    // compute mapping: 16x16 threads, each 8x8 outputs
    const int tx = tid & 15;   // n-group
    const int ty = tid >> 4;   // m-group

    float acc[8][8] = {};

    for (int k0 = 0; k0 < K; k0 += 8) {
        float4 a = *(const float4*)(Arow + k0);
        float4 b = *(const float4*)(Brow + k0);
        __syncthreads();
        As[lk + 0][lm] = a.x; As[lk + 1][lm] = a.y;
        As[lk + 2][lm] = a.z; As[lk + 3][lm] = a.w;
        Bs[lk + 0][lm] = b.x; Bs[lk + 1][lm] = b.y;
        Bs[lk + 2][lm] = b.z; Bs[lk + 3][lm] = b.w;
        __syncthreads();
#pragma unroll
        for (int kk = 0; kk < 8; ++kk) {
            float av[8], bv[8];
            *(float4*)&av[0] = *(const float4*)&As[kk][ty * 8];
            *(float4*)&av[4] = *(const float4*)&As[kk][ty * 8 + 4];
            *(float4*)&bv[0] = *(const float4*)&Bs[kk][tx * 8];
            *(float4*)&bv[4] = *(const float4*)&Bs[kk][tx * 8 + 4];
#pragma unroll
            for (int i = 0; i < 8; ++i)
#pragma unroll
                for (int j = 0; j < 8; ++j)
                    acc[i][j] = fmaf(av[i], bv[j], acc[i][j]);
        }
    }

#pragma unroll
    for (int i = 0; i < 8; ++i) {
        float* Crow = C + (size_t)(bm * 128 + ty * 8 + i) * N + bn * 128 + tx * 8;
        *(float4*)Crow = make_float4(acc[i][0], acc[i][1], acc[i][2], acc[i][3]);
        *((float4*)Crow + 1) = make_float4(acc[i][4], acc[i][5], acc[i][6], acc[i][7]);
    }
}

// Layer-1 scan: 262144 threads, one per (b, n).  C1 rows t=0..97; writes
// S1 rows t=0 (zeros) .. t=98.  Row layout: (t*256+b)*1024 + n = t*262144 + idx.
__global__ __launch_bounds__(256) void scan1(const float* __restrict__ C1,
                                             float* __restrict__ S1) {
    const int idx = blockIdx.x * 256 + threadIdx.x;   // 0..262143
    S1[idx] = 0.0f;                                    // t = 0 row block
    float I = 0.0f, V = 0.0f;
    for (int t = 1; t <= 98; ++t) {
        float c = C1[(size_t)(t - 1) * 262144 + idx];
        I = ALPHA_F * I + c;
        float Vp = BETA_F * V + ONE_MINUS_BETA_F * I;
        float s = (Vp > 1.0f) ? 1.0f : 0.0f;
        V = (1.0f - s) * Vp;
        S1[(size_t)t * 262144 + idx] = s;
    }
}

// Layer-2 scan: 65536 threads, one per (b, n2).  C2 rows t=0..98; writes
// out rows t=0 (zeros) .. t=99.  Row layout: t*65536 + idx.
__global__ __launch_bounds__(256) void scan2(const float* __restrict__ C2,
                                             float* __restrict__ out) {
    const int idx = blockIdx.x * 256 + threadIdx.x;   // 0..65535
    out[idx] = 0.0f;                                   // t = 0
    float I = 0.0f, V = 0.0f;
    for (int t = 1; t <= 99; ++t) {
        float c = C2[(size_t)(t - 1) * 65536 + idx];
        I = ALPHA_F * I + c;
        float Vp = BETA_F * V + ONE_MINUS_BETA_F * I;
        float s = (Vp > 1.0f) ? 1.0f : 0.0f;
        V = (1.0f - s) * Vp;
        out[(size_t)t * 65536 + idx] = s;
    }
}

extern "C" void kernel_launch(void* const* d_in, const int* in_sizes, int n_in,
                              void* d_out, int out_size, void* d_ws, size_t ws_size,
                              hipStream_t stream) {
    const float* x  = (const float*)d_in[0];   // [100,256,784]
    const float* W1 = (const float*)d_in[1];   // [1024,784]
    const float* W2 = (const float*)d_in[2];   // [256,1024]
    float* out = (float*)d_out;                // [100,256,256]

    // Workspace layout (C2 aliases C1: C1 is dead after scan1, and GEMM2
    // runs after scan1 on the same stream).
    float* C1 = (float*)d_ws;                  // 25088*1024 floats = 102.8 MB
    float* S1 = C1 + (size_t)25088 * 1024;     // 25344*1024 floats = 103.8 MB
    float* C2 = C1;                            // 25344*256 floats (aliased)

    // GEMM1: M=25088 (t=0..97), N=1024, K=784
    sgemm_nt<<<dim3(25088 / 128, 1024 / 128), 256, 0, stream>>>(x, W1, C1, 25088, 1024, 784);
    // scan1 -> S1 (rows t=0..98)
    scan1<<<262144 / 256, 256, 0, stream>>>(C1, S1);
    // GEMM2: M=25344 (t=0..98), N=256, K=1024
    sgemm_nt<<<dim3(25344 / 128, 256 / 128), 256, 0, stream>>>(S1, W2, C2, 25344, 256, 1024);
    // scan2 -> out (rows t=0..99)
    scan2<<<65536 / 256, 256, 0, stream>>>(C2, out);
}

// Round 2
// 345.453 us; speedup vs baseline: 2.3199x; 2.3199x over previous
//
#include <hip/hip_runtime.h>
#include <hip/hip_bf16.h>

// SNN EventProp LIF forward, 2 layers: 784 -> 1024 -> 256, T=100, B=256.
//
// Key structure: (1) LIF current I is LINEAR in the per-step matmul results,
// so all T matmuls of a layer collapse into one batched op + a cheap
// per-(b,n) time scan. (2) Both matmul inputs are BINARY spike trains
// (x ~5% dense; layer-1 spike output is ~4.4 sigma rare), so each "GEMM" is
// really a sparse gather-ADD of weight rows (no multiplies, fp32-exact):
//     C[r,:] = sum_{k: act[r,k]==1} WT[k,:]
//
// Pipeline:
//   transpose W1 -> W1T [784,1024], W2 -> W2T [1024,256]
//   sparse1: C1[25088,1024] from x rows t=0..97        (one block per row)
//   scan1  : S1u8[25344,1024] spikes (t=0 zeroed)
//   sparse2: C2[25344,256] from S1u8  (nearly-empty rows -> almost free)
//   scan2  : out[100,256,256] (t=0 zero + t=1..99)
//
// ALPHA=0.8f, BETA=0.95f, 1-BETA=0.05f (exact float32 of the Python consts).

#define ALPHA_F 0.8f
#define BETA_F 0.95f
#define ONE_MINUS_BETA_F 0.05f

// WT[k*N + n] = W[n*K + k].  W: [N,K] row-major.
__global__ __launch_bounds__(256) void transpose_nt(const float* __restrict__ W,
                                                    float* __restrict__ WT,
                                                    int N, int K) {
    __shared__ float tile[32][33];
    const int k0 = blockIdx.x * 32, n0 = blockIdx.y * 32;
    const int tx = threadIdx.x & 31, ty = threadIdx.x >> 5;   // 32 x 8
#pragma unroll
    for (int r = 0; r < 4; ++r) {
        int n = n0 + ty + r * 8, k = k0 + tx;
        if (n < N && k < K) tile[ty + r * 8][tx] = W[(size_t)n * K + k];
    }
    __syncthreads();
#pragma unroll
    for (int r = 0; r < 4; ++r) {
        int k = k0 + ty + r * 8, n = n0 + tx;
        if (k < K && n < N) WT[(size_t)k * N + n] = tile[tx][ty + r * 8];
    }
}

// One block per output row. act row is binary; compact active k's into LDS,
// then every thread accumulates NC columns (cols tid + j*256) by summing
// WT rows. N = NC*256. No multiplies: spike==1 -> add the weight.
template <typename AT, int NC>
__global__ __launch_bounds__(256) void sparse_accum(const AT* __restrict__ act,
                                                    const float* __restrict__ WT,
                                                    float* __restrict__ C, int K) {
    constexpr int N = NC * 256;
    __shared__ unsigned short list[1024];
    __shared__ int cnt;
    const int tid = threadIdx.x;
    const int row = blockIdx.x;
    if (tid == 0) cnt = 0;
    __syncthreads();
    const AT* ar = act + (size_t)row * K;
    for (int c = tid; c < K; c += 256) {
        if (ar[c] != (AT)0) { int p = atomicAdd(&cnt, 1); list[p] = (unsigned short)c; }
    }
    __syncthreads();
    const int n = cnt;
    float acc[NC];
#pragma unroll
    for (int j = 0; j < NC; ++j) acc[j] = 0.0f;
    int i = 0;
    for (; i + 2 <= n; i += 2) {   // 2-wide: 2*NC independent loads in flight
        const float* w0 = WT + (size_t)list[i] * N + tid;
        const float* w1 = WT + (size_t)list[i + 1] * N + tid;
#pragma unroll
        for (int j = 0; j < NC; ++j) acc[j] += w0[j * 256];
#pragma unroll
        for (int j = 0; j < NC; ++j) acc[j] += w1[j * 256];
    }
    if (i < n) {
        const float* w0 = WT + (size_t)list[i] * N + tid;
#pragma unroll
        for (int j = 0; j < NC; ++j) acc[j] += w0[j * 256];
    }
    float* Cr = C + (size_t)row * N + tid;
#pragma unroll
    for (int j = 0; j < NC; ++j) Cr[j * 256] = acc[j];
}

// Layer-1 scan: one thread per (b,n1), idx in [0, 262144). C1 rows t=0..97.
// Writes S1 (uint8 spikes) rows t=0 (zeros) .. 98. Row layout t*262144+idx.
__global__ __launch_bounds__(256) void scan1(const float* __restrict__ C1,
                                             unsigned char* __restrict__ S1) {
    const int idx = blockIdx.x * 256 + threadIdx.x;
    S1[idx] = 0;                                       // t = 0
    float I = 0.0f, V = 0.0f;
    for (int t = 1; t <= 98; ++t) {
        float c = C1[(size_t)(t - 1) * 262144 + idx];
        I = ALPHA_F * I + c;
        float Vp = BETA_F * V + ONE_MINUS_BETA_F * I;
        float s = (Vp > 1.0f) ? 1.0f : 0.0f;
        V = (1.0f - s) * Vp;
        S1[(size_t)t * 262144 + idx] = (unsigned char)s;
    }
}

// Layer-2 scan: one thread per (b,n2), idx in [0, 65536). C2 rows t=0..98.
__global__ __launch_bounds__(256) void scan2(const float* __restrict__ C2,
                                             float* __restrict__ out) {
    const int idx = blockIdx.x * 256 + threadIdx.x;
    out[idx] = 0.0f;                                   // t = 0
    float I = 0.0f, V = 0.0f;
    for (int t = 1; t <= 99; ++t) {
        float c = C2[(size_t)(t - 1) * 65536 + idx];
        I = ALPHA_F * I + c;
        float Vp = BETA_F * V + ONE_MINUS_BETA_F * I;
        float s = (Vp > 1.0f) ? 1.0f : 0.0f;
        V = (1.0f - s) * Vp;
        out[(size_t)t * 65536 + idx] = s;
    }
}

extern "C" void kernel_launch(void* const* d_in, const int* in_sizes, int n_in,
                              void* d_out, int out_size, void* d_ws, size_t ws_size,
                              hipStream_t stream) {
    const float* x  = (const float*)d_in[0];   // [100,256,784] binary
    const float* W1 = (const float*)d_in[1];   // [1024,784]
    const float* W2 = (const float*)d_in[2];   // [256,1024]
    float* out = (float*)d_out;                // [100,256,256]

    // Workspace layout (bytes):
    //   C1   : 25088*1024*4 = 102,760,448   (C2 aliases C1 -- C1 dead after scan1)
    //   S1u8 : 25344*1024   =  25,952,256
    //   W1T  : 784*1024*4   =   3,211,264
    //   W2T  : 1024*256*4   =   1,048,576
    // total ~133 MB (< round-1's 207 MB footprint, known to fit ws_size)
    char* ws = (char*)d_ws;
    float* C1 = (float*)ws;
    unsigned char* S1 = (unsigned char*)(ws + (size_t)25088 * 1024 * 4);
    float* W1T = (float*)(ws + (size_t)25088 * 1024 * 4 + (size_t)25344 * 1024);
    float* W2T = W1T + (size_t)784 * 1024;
    float* C2 = C1;

    transpose_nt<<<dim3(25, 32), 256, 0, stream>>>(W1, W1T, 1024, 784);
    transpose_nt<<<dim3(32, 8), 256, 0, stream>>>(W2, W2T, 256, 1024);

    // layer 1: rows r = t*256+b, t=0..97
    sparse_accum<float, 4><<<25088, 256, 0, stream>>>(x, W1T, C1, 784);
    scan1<<<262144 / 256, 256, 0, stream>>>(C1, S1);

    // layer 2: rows t=0..98 of S1
    sparse_accum<unsigned char, 1><<<25344, 256, 0, stream>>>(S1, W2T, C2, 1024);
    scan2<<<65536 / 256, 256, 0, stream>>>(C2, out);
}